// Round 1
// baseline (1168.152 us; speedup 1.0000x reference)
//
#include <hip/hip_runtime.h>
#include <hip/hip_bf16.h>

#define BB 256
#define HH 256
#define SSL 512
#define G3 768

using short8 = __attribute__((ext_vector_type(8))) short;
using f32x4  = __attribute__((ext_vector_type(4))) float;

__device__ __forceinline__ unsigned short f2bf(float f) {
  unsigned int u = __float_as_uint(f);
  u += 0x7FFFu + ((u >> 16) & 1u);
  return (unsigned short)(u >> 16);
}
__device__ __forceinline__ float bf2f(unsigned short b) {
  return __uint_as_float(((unsigned int)b) << 16);
}
// barrier that does NOT drain vmcnt (keeps global prefetch in flight);
// lgkmcnt(0) orders all LDS traffic across the barrier.
__device__ __forceinline__ void block_sync_lds() {
  asm volatile("s_waitcnt lgkmcnt(0)\n\ts_barrier" ::: "memory");
}

// ---------------------------------------------------------------------------
// Kernel 1: GI[b][s][j] = sum_h X[b][h][s] * Wih[j][h] + bih[j]   (bf16 out)
// grid (1024, 6), block 512.  tile: 128 m (=s) x 128 j, BK=64.
// ---------------------------------------------------------------------------
__global__ __launch_bounds__(512, 4) void gi_gemm(
    const float* __restrict__ X, const float* __restrict__ Wih,
    const float* __restrict__ bih, unsigned short* __restrict__ gi)
{
  __shared__ __align__(16) char smem[36864];
  unsigned short (*Al)[72] = (unsigned short(*)[72])smem;           // 128 x 72 bf16
  unsigned short (*Bl)[72] = (unsigned short(*)[72])(smem + 18432); // 128 x 72 bf16
  float (*Dl)[132] = (float(*)[132])smem;                           // 64 x 132 f32 (epilogue)

  const int tid  = threadIdx.x;
  const int lane = tid & 63;
  const int wave = tid >> 6;
  const int wm   = wave >> 2;   // 0..1  (m 64-half)
  const int wj   = wave & 3;    // 0..3  (j 32-slice)
  const int n16  = lane & 15;
  const int quad = lane >> 4;

  const int mblk = blockIdx.x;          // 0..1023
  const int b    = mblk >> 2;
  const int s0   = (mblk & 3) * 128;
  const int j0   = blockIdx.y * 128;

  f32x4 acc[4][2];
#pragma unroll
  for (int mt = 0; mt < 4; mt++)
#pragma unroll
    for (int jt = 0; jt < 2; jt++) acc[mt][jt] = f32x4{0.f, 0.f, 0.f, 0.f};

  const float* Xb = X + (size_t)b * (HH * SSL);

  for (int kt = 0; kt < 4; kt++) {
    // stage A: 64 h-rows x 128 s (coalesced along s), transpose to [m=s][k=h]
#pragma unroll
    for (int i = 0; i < 4; i++) {
      int hl = (tid >> 5) + 16 * i;       // 0..63
      int s4 = tid & 31;
      const float4 v = *(const float4*)(Xb + (size_t)(kt * 64 + hl) * SSL + s0 + 4 * s4);
      Al[4 * s4 + 0][hl] = f2bf(v.x);
      Al[4 * s4 + 1][hl] = f2bf(v.y);
      Al[4 * s4 + 2][hl] = f2bf(v.z);
      Al[4 * s4 + 3][hl] = f2bf(v.w);
    }
    // stage B: 128 j x 64 k, k contiguous
#pragma unroll
    for (int i = 0; i < 4; i++) {
      int j  = (tid >> 4) + 32 * i;       // 0..127
      int k4 = tid & 15;
      const float4 v = *(const float4*)(Wih + (size_t)(j0 + j) * HH + kt * 64 + 4 * k4);
      unsigned long long pk = (unsigned long long)f2bf(v.x)
          | ((unsigned long long)f2bf(v.y) << 16)
          | ((unsigned long long)f2bf(v.z) << 32)
          | ((unsigned long long)f2bf(v.w) << 48);
      *(unsigned long long*)&Bl[j][4 * k4] = pk;
    }
    __syncthreads();
#pragma unroll
    for (int kk = 0; kk < 2; kk++) {
      short8 af[4], bfr[2];
#pragma unroll
      for (int mt = 0; mt < 4; mt++)
        af[mt] = *(const short8*)&Al[wm * 64 + mt * 16 + n16][kk * 32 + quad * 8];
#pragma unroll
      for (int jt = 0; jt < 2; jt++)
        bfr[jt] = *(const short8*)&Bl[wj * 32 + jt * 16 + n16][kk * 32 + quad * 8];
#pragma unroll
      for (int mt = 0; mt < 4; mt++)
#pragma unroll
        for (int jt = 0; jt < 2; jt++)
          acc[mt][jt] = __builtin_amdgcn_mfma_f32_16x16x32_bf16(af[mt], bfr[jt], acc[mt][jt], 0, 0, 0);
    }
    __syncthreads();
  }

  float bias[2];
  bias[0] = bih[j0 + wj * 32 + 0 * 16 + n16];
  bias[1] = bih[j0 + wj * 32 + 1 * 16 + n16];

  // epilogue via LDS transpose, 2 chunks of 64 rows
  for (int c = 0; c < 2; c++) {
    __syncthreads();
    if (wm == c) {
#pragma unroll
      for (int mt = 0; mt < 4; mt++)
#pragma unroll
        for (int jt = 0; jt < 2; jt++)
#pragma unroll
          for (int r = 0; r < 4; r++)
            Dl[mt * 16 + quad * 4 + r][wj * 32 + jt * 16 + n16] = acc[mt][jt][r] + bias[jt];
    }
    __syncthreads();
#pragma unroll
    for (int i = 0; i < 2; i++) {
      int ml = (tid >> 4) + 32 * i;       // 0..63
      int jj = (tid & 15) * 8;
      float4 p0 = *(const float4*)&Dl[ml][jj];
      float4 p1 = *(const float4*)&Dl[ml][jj + 4];
      short8 st;
      st[0] = (short)f2bf(p0.x); st[1] = (short)f2bf(p0.y);
      st[2] = (short)f2bf(p0.z); st[3] = (short)f2bf(p0.w);
      st[4] = (short)f2bf(p1.x); st[5] = (short)f2bf(p1.y);
      st[6] = (short)f2bf(p1.z); st[7] = (short)f2bf(p1.w);
      int sgl = s0 + c * 64 + ml;
      *(short8*)(gi + ((size_t)b * SSL + sgl) * G3 + j0 + jj) = st;
    }
  }
}

// ---------------------------------------------------------------------------
// Kernel 2: persistent GRU scan. grid 64 blocks x 4 batch rows, 512 threads.
// W_hh bf16 register-resident as MFMA A-fragments (192 VGPR/lane).
// ---------------------------------------------------------------------------
__global__ __launch_bounds__(512, 2) void gru_scan(
    const float* __restrict__ tree, const int* __restrict__ mask,
    const float* __restrict__ Whh, const float* __restrict__ bhh,
    const unsigned short* __restrict__ gi, float* __restrict__ out)
{
  __shared__ unsigned short h_bf[16][264];  // bf16 h, rows 4..15 stay zero
  __shared__ float h_f32[4][256];           // fp32 master h
  __shared__ float pre[3][4][260];          // gh pre-activations (r,z,n)
  __shared__ int lsum[4];

  const int tid  = threadIdx.x;
  const int lane = tid & 63;
  const int wave = tid >> 6;     // 0..7 -> j-slice [32w, 32w+32)
  const int n16  = lane & 15;
  const int quad = lane >> 4;
  const int brow0 = blockIdx.x * 4;

  for (int i = tid; i < 16 * 264; i += 512) ((unsigned short*)h_bf)[i] = 0;
  if (tid < 4) lsum[tid] = 0;
  __syncthreads();

  const int bb = tid >> 7;            // 0..3
  const int j0 = (tid & 127) * 2;     // even j

  {
    float a0 = tree[(size_t)(brow0 + bb) * HH + j0];
    float a1 = tree[(size_t)(brow0 + bb) * HH + j0 + 1];
    h_f32[bb][j0] = a0; h_f32[bb][j0 + 1] = a1;
    *(unsigned int*)&h_bf[bb][j0] = (unsigned int)f2bf(a0) | ((unsigned int)f2bf(a1) << 16);
  }
  {
    int part = tid & 127;
    const int* mp = mask + (size_t)(brow0 + bb) * SSL + part * 4;
    atomicAdd(&lsum[bb], mp[0] + mp[1] + mp[2] + mp[3]);
  }
  float bhr0 = bhh[0 * HH + j0], bhr1 = bhh[0 * HH + j0 + 1];
  float bhz0 = bhh[1 * HH + j0], bhz1 = bhh[1 * HH + j0 + 1];
  float bhn0 = bhh[2 * HH + j0], bhn1 = bhh[2 * HH + j0 + 1];

  // preload W_hh fragments: wave w, gate g, m-tile mt, k-tile kt
  short8 aw[3][2][8];
#pragma unroll
  for (int g = 0; g < 3; g++)
#pragma unroll
    for (int mt = 0; mt < 2; mt++)
#pragma unroll
      for (int kt = 0; kt < 8; kt++) {
        int row = g * HH + wave * 32 + mt * 16 + n16;
        int k0  = kt * 32 + quad * 8;
        const float4 v0 = *(const float4*)(Whh + (size_t)row * HH + k0);
        const float4 v1 = *(const float4*)(Whh + (size_t)row * HH + k0 + 4);
        short8 w;
        w[0] = (short)f2bf(v0.x); w[1] = (short)f2bf(v0.y);
        w[2] = (short)f2bf(v0.z); w[3] = (short)f2bf(v0.w);
        w[4] = (short)f2bf(v1.x); w[5] = (short)f2bf(v1.y);
        w[6] = (short)f2bf(v1.z); w[7] = (short)f2bf(v1.w);
        aw[g][mt][kt] = w;
      }

  __syncthreads();
  int last = lsum[bb] - 1; if (last < 0) last = 0;

  const unsigned short* gib = gi + (size_t)(brow0 + bb) * SSL * G3;
  unsigned int giA[3], giB[3];
#pragma unroll
  for (int g = 0; g < 3; g++) giA[g] = *(const unsigned int*)(gib + (size_t)0 * G3 + g * HH + j0);
#pragma unroll
  for (int g = 0; g < 3; g++) giB[g] = *(const unsigned int*)(gib + (size_t)1 * G3 + g * HH + j0);

  auto step = [&](int t, unsigned int* gv) {
    // ---- phase A: gh = Whh . h (MFMA) ----
    f32x4 acc[3][2];
#pragma unroll
    for (int g = 0; g < 3; g++)
#pragma unroll
      for (int mt = 0; mt < 2; mt++) acc[g][mt] = f32x4{0.f, 0.f, 0.f, 0.f};
#pragma unroll
    for (int kt = 0; kt < 8; kt++) {
      short8 hb = *(const short8*)&h_bf[n16][kt * 32 + quad * 8];
#pragma unroll
      for (int g = 0; g < 3; g++)
#pragma unroll
        for (int mt = 0; mt < 2; mt++)
          acc[g][mt] = __builtin_amdgcn_mfma_f32_16x16x32_bf16(aw[g][mt][kt], hb, acc[g][mt], 0, 0, 0);
    }
    if (n16 < 4) {
#pragma unroll
      for (int g = 0; g < 3; g++)
#pragma unroll
        for (int mt = 0; mt < 2; mt++)
#pragma unroll
          for (int r = 0; r < 4; r++)
            pre[g][n16][wave * 32 + mt * 16 + quad * 4 + r] = acc[g][mt][r];
    }
    // consume this step's gi from regs, then issue prefetch for t+2
    float gir0 = bf2f((unsigned short)(gv[0] & 0xFFFF)), gir1 = bf2f((unsigned short)(gv[0] >> 16));
    float giz0 = bf2f((unsigned short)(gv[1] & 0xFFFF)), giz1 = bf2f((unsigned short)(gv[1] >> 16));
    float gin0 = bf2f((unsigned short)(gv[2] & 0xFFFF)), gin1 = bf2f((unsigned short)(gv[2] >> 16));
    int tn = (t + 2 < SSL) ? t + 2 : SSL - 1;
    gv[0] = *(const unsigned int*)(gib + (size_t)tn * G3 + 0 * HH + j0);
    gv[1] = *(const unsigned int*)(gib + (size_t)tn * G3 + 1 * HH + j0);
    gv[2] = *(const unsigned int*)(gib + (size_t)tn * G3 + 2 * HH + j0);
    block_sync_lds();
    // ---- phase B: gates + state update (fp32) ----
    float hr0 = pre[0][bb][j0] + bhr0, hr1 = pre[0][bb][j0 + 1] + bhr1;
    float hz0 = pre[1][bb][j0] + bhz0, hz1 = pre[1][bb][j0 + 1] + bhz1;
    float hn0 = pre[2][bb][j0] + bhn0, hn1 = pre[2][bb][j0 + 1] + bhn1;
    float r0 = __builtin_amdgcn_rcpf(1.f + __expf(-(gir0 + hr0)));
    float r1 = __builtin_amdgcn_rcpf(1.f + __expf(-(gir1 + hr1)));
    float z0 = __builtin_amdgcn_rcpf(1.f + __expf(-(giz0 + hz0)));
    float z1 = __builtin_amdgcn_rcpf(1.f + __expf(-(giz1 + hz1)));
    float a0 = gin0 + r0 * hn0, a1 = gin1 + r1 * hn1;
    float nn0 = 1.f - 2.f * __builtin_amdgcn_rcpf(__expf(2.f * a0) + 1.f);
    float nn1 = 1.f - 2.f * __builtin_amdgcn_rcpf(__expf(2.f * a1) + 1.f);
    float ho0 = h_f32[bb][j0], ho1 = h_f32[bb][j0 + 1];
    float hN0 = nn0 + z0 * (ho0 - nn0);
    float hN1 = nn1 + z1 * (ho1 - nn1);
    h_f32[bb][j0] = hN0; h_f32[bb][j0 + 1] = hN1;
    *(unsigned int*)&h_bf[bb][j0] = (unsigned int)f2bf(hN0) | ((unsigned int)f2bf(hN1) << 16);
    if (t == last) {
      out[(size_t)(brow0 + bb) * HH + j0] = hN0;
      out[(size_t)(brow0 + bb) * HH + j0 + 1] = hN1;
    }
    block_sync_lds();
  };

  for (int t = 0; t < SSL; t += 2) {
    step(t, giA);
    step(t + 1, giB);
  }
}

extern "C" void kernel_launch(void* const* d_in, const int* in_sizes, int n_in,
                              void* d_out, int out_size, void* d_ws, size_t ws_size,
                              hipStream_t stream) {
  const float* tree = (const float*)d_in[0];
  const float* seq  = (const float*)d_in[1];
  const int*   mask = (const int*)d_in[2];
  const float* Wih  = (const float*)d_in[3];
  const float* Whh  = (const float*)d_in[4];
  const float* bih  = (const float*)d_in[5];
  const float* bhh  = (const float*)d_in[6];
  float* out = (float*)d_out;
  unsigned short* gi = (unsigned short*)d_ws;  // 256*512*768 bf16 = 201.3 MB

  gi_gemm<<<dim3(1024, 6), 512, 0, stream>>>(seq, Wih, bih, gi);
  gru_scan<<<dim3(64), 512, 0, stream>>>(tree, mask, Whh, bhh, gi, out);
}